// Round 7
// baseline (222.437 us; speedup 1.0000x reference)
//
#include <hip/hip_runtime.h>
#include <stdint.h>

#define BATCH 4096
#define IN_DIM 1024
#define HID 1024
#define KDIM 2048      // IN + HID
#define NGATE 4096     // 4 * HID
#define EPITCH 264     // epilogue LDS row pitch (shorts); 264*2B = 16B-aligned
#define BK 64          // K-tile
#define BM 256         // M-tile
#define BN 256         // N-tile

typedef __attribute__((ext_vector_type(4))) float floatx4;
typedef __attribute__((ext_vector_type(8))) __bf16 bf16x8;
typedef __attribute__((ext_vector_type(8))) unsigned short ushort8;

__device__ __forceinline__ unsigned short f2bf(float f) {
    union { float f; unsigned int u; } v; v.f = f;
    unsigned int u = v.u;
    u += 0x7fffu + ((u >> 16) & 1u);   // RNE; inputs finite
    return (unsigned short)(u >> 16);
}
__device__ __forceinline__ float bf2f(unsigned short s) {
    union { unsigned int u; float f; } v; v.u = ((unsigned int)s) << 16;
    return v.f;
}
__device__ __forceinline__ ushort8 cvt8(const float* __restrict__ src) {
    float4 v0 = ((const float4*)src)[0];
    float4 v1 = ((const float4*)src)[1];
    ushort8 o = { f2bf(v0.x), f2bf(v0.y), f2bf(v0.z), f2bf(v0.w),
                  f2bf(v1.x), f2bf(v1.y), f2bf(v1.z), f2bf(v1.w) };
    return o;
}

// ---------------------------------------------------------------------------
// prep (unchanged from R6; block-uniform source routing):
//   X  = [x | h] bf16 (4096 x 2048)
//   W  = GATE-INTERLEAVED rows: W-row (u*4+gate) = [w_gate_i[u] | w_gate_h[u]]
//   bias[u*4+gate] = b_gate_i[u] + b_gate_h[u]
// ---------------------------------------------------------------------------
__global__ __launch_bounds__(256) void prep_kernel(
    const float* __restrict__ x,  const float* __restrict__ h,
    const float* __restrict__ wii, const float* __restrict__ wih,
    const float* __restrict__ wfi, const float* __restrict__ wfh,
    const float* __restrict__ wgi, const float* __restrict__ wgh,
    const float* __restrict__ woi, const float* __restrict__ woh,
    const float* __restrict__ bii, const float* __restrict__ bih,
    const float* __restrict__ bfi, const float* __restrict__ bfh,
    const float* __restrict__ bgi, const float* __restrict__ bgh,
    const float* __restrict__ boi, const float* __restrict__ boh,
    unsigned short* __restrict__ Xb,
    unsigned short* __restrict__ Wb,
    float* __restrict__ bias)
{
    const int bid = blockIdx.x;
    const int tid = threadIdx.x;

    if (bid < 2048) {                       // x -> Xb left half
        const int e = (bid * 256 + tid) * 8;
        const int b = e >> 10, k = e & 1023;
        *(ushort8*)(Xb + (size_t)b * KDIM + k) = cvt8(x + e);
    } else if (bid < 4096) {                // h -> Xb right half
        const int e = ((bid - 2048) * 256 + tid) * 8;
        const int b = e >> 10, k = e & 1023;
        *(ushort8*)(Xb + (size_t)b * KDIM + 1024 + k) = cvt8(h + e);
    } else if (bid < 8192) {                // weights -> interleaved W rows
        const int m   = (bid - 4096) >> 9;          // 0..7, block-uniform
        const int off = (bid - 4096) & 511;
        const int e = (off * 256 + tid) * 8;
        const int n = e >> 10, k = e & 1023;
        const float* src;
        switch (m) {
            case 0: src = wii; break; case 1: src = wih; break;
            case 2: src = wfi; break; case 3: src = wfh; break;
            case 4: src = wgi; break; case 5: src = wgh; break;
            case 6: src = woi; break; default: src = woh; break;
        }
        const int gate = m >> 1, part = m & 1;
        *(ushort8*)(Wb + (size_t)(n * 4 + gate) * KDIM + part * 1024 + k)
            = cvt8(src + e);
    } else {                                // bias: 16 blocks x 256 elems
        const int t = (bid - 8192) * 256 + tid;     // 0..4095 = gate*1024+n
        const int gate = (bid - 8192) >> 2;         // block-uniform
        const int n = t & 1023;
        const float *bi, *bh_;
        switch (gate) {
            case 0: bi = bii; bh_ = bih; break;
            case 1: bi = bfi; bh_ = bfh; break;
            case 2: bi = bgi; bh_ = bgh; break;
            default: bi = boi; bh_ = boh; break;
        }
        bias[n * 4 + gate] = bi[n] + bh_[n];
    }
}

// ---------------------------------------------------------------------------
// gemm_lstm: preact = X.W^T + bias, cols interleaved (col = u*4+gate).
// 256x256 tile, BK=64, 1024 threads (16 waves as 4m x 4n, 64x64 each).
// 4 GLD16/thread/iter (A:2, B:2), 32 MFMA per barrier pair per wave.
// XOR chunk swizzle (R5, conflict-free): store chunk (row,kc) at kc^(row&7);
// read with co = ((t*4+quad) ^ (idx&7))*8.
// Fused epilogue in 4 quarter-tile phases (64 rows each) through
// E[64][EPITCH] (aliases As), fully-coalesced float4 h'/c' stores.
// ---------------------------------------------------------------------------
#define GLD16(g, l)                                                          \
    __builtin_amdgcn_global_load_lds(                                        \
        (__attribute__((address_space(1))) void*)(g),                        \
        (__attribute__((address_space(3))) void*)(l), 16, 0, 0)

__global__ __launch_bounds__(1024) void gemm_lstm(
    const unsigned short* __restrict__ X,
    const unsigned short* __restrict__ W,
    const float* __restrict__ bias,
    const float* __restrict__ c_in,
    float* __restrict__ out)
{
    __shared__ __align__(16) unsigned char smem[65536];      // 64 KB
    unsigned short* As = (unsigned short*)smem;              // 256*64 shorts, 32 KB
    unsigned short* Bs = (unsigned short*)(smem + 32768);    // 256*64 shorts, 32 KB
    unsigned short* E  = (unsigned short*)smem;              // 64 x EPITCH, 33.8 KB

    const int tid  = threadIdx.x;
    const int wave = tid >> 6;
    const int lane = tid & 63;
    const int quad = lane >> 4, idx = lane & 15;
    const int wm = (wave >> 2) * 64;      // 0,64,128,192
    const int wn = (wave & 3) * 64;       // 0,64,128,192

    const int rowA0 = blockIdx.x * BM;
    const int rowB0 = blockIdx.y * BN;

    // staging: srow = tid>>3 (0..127); per-thread k-offset includes xor swizzle
    const int srow = tid >> 3;
    const int skk  = ((tid & 7) ^ (srow & 7)) * 8;
    const unsigned short* gA = X + (size_t)(rowA0 + srow) * KDIM + skk;
    const unsigned short* gB = W + (size_t)(rowB0 + srow) * KDIM + skk;
    const size_t rstride = (size_t)128 * KDIM;   // +128 rows per issue

    const int swz = (idx & 7);

    floatx4 acc[4][4] = {};

    for (int k0 = 0; k0 < KDIM; k0 += BK) {
#pragma unroll
        for (int r = 0; r < 2; ++r) {
            GLD16(gA + k0 + r * rstride, As + (r * 1024 + tid) * 8);
            GLD16(gB + k0 + r * rstride, Bs + (r * 1024 + tid) * 8);
        }
        __syncthreads();

        bf16x8 af[4][2], bfr[4][2];
#pragma unroll
        for (int t = 0; t < 2; ++t) {
            const int co = ((t * 4 + quad) ^ swz) * 8;
#pragma unroll
            for (int i = 0; i < 4; ++i)
                af[i][t] = *(const bf16x8*)(As + (wm + i * 16 + idx) * BK + co);
#pragma unroll
            for (int j = 0; j < 4; ++j)
                bfr[j][t] = *(const bf16x8*)(Bs + (wn + j * 16 + idx) * BK + co);
        }
#pragma unroll
        for (int t = 0; t < 2; ++t)
#pragma unroll
            for (int i = 0; i < 4; ++i)
#pragma unroll
                for (int j = 0; j < 4; ++j)
                    acc[i][j] = __builtin_amdgcn_mfma_f32_16x16x32_bf16(
                        af[i][t], bfr[j][t], acc[i][j], 0, 0, 0);
        __syncthreads();
    }

    // ---- fused epilogue, four quarter-tile phases (64 rows each) ----
    const int g = idx & 3;
    const int rowo = tid >> 4;           // 0..63 (stage 2)
    const int chk  = tid & 15;           // 0..15 float4-chunk of u
    float* __restrict__ out_h = out;
    float* __restrict__ out_c = out + (size_t)BATCH * HID;

#pragma unroll
    for (int ph = 0; ph < 4; ++ph) {
        // stage 1: the 4 waves owning rows [ph*64, ph*64+64) write gates to E
        if ((wave >> 2) == ph) {
#pragma unroll
            for (int j = 0; j < 4; ++j) {
                const int col = wn + j * 16 + idx;
                const float bv = bias[rowB0 + col];
#pragma unroll
                for (int i = 0; i < 4; ++i) {
#pragma unroll
                    for (int r = 0; r < 4; ++r) {
                        const int row = i * 16 + quad * 4 + r;   // 0..63
                        const float v  = acc[i][j][r] + bv;
                        const float vv = (g == 2) ? 2.f * v : v;
                        const float s  = 1.f / (1.f + __expf(-vv));
                        const float a  = (g == 2) ? 2.f * s - 1.f : s;
                        E[row * EPITCH + col] = f2bf(a);
                    }
                }
            }
        }
        __syncthreads();

        // stage 2: all 1024 threads combine 64 rows x 64 u in one pass
        {
            const int row_g = rowA0 + ph * 64 + rowo;
            const int colc  = chk * 16;                 // 4 u * 4 gates
            ushort8 e0 = *(const ushort8*)(E + rowo * EPITCH + colc);
            ushort8 e1 = *(const ushort8*)(E + rowo * EPITCH + colc + 8);
            const int u0 = (rowB0 >> 2) + chk * 4;
            const float4 cv = *(const float4*)(c_in + (size_t)row_g * HID + u0);

            float cvv[4] = { cv.x, cv.y, cv.z, cv.w };
            float hp[4], cp[4];
#pragma unroll
            for (int d = 0; d < 4; ++d) {
                const ushort8& e = (d < 2) ? e0 : e1;
                const int b = (d & 1) * 4;
                const float iv = bf2f(e[b + 0]);
                const float fv = bf2f(e[b + 1]);
                const float gv = bf2f(e[b + 2]);
                const float ov = bf2f(e[b + 3]);
                const float c2 = fv * cvv[d] + iv * gv;
                const float e2 = __expf(2.f * c2);
                cp[d] = c2;
                hp[d] = ov * ((e2 - 1.f) / (e2 + 1.f));
            }
            float4 hv  = { hp[0], hp[1], hp[2], hp[3] };
            float4 cpv = { cp[0], cp[1], cp[2], cp[3] };
            *(float4*)(out_h + (size_t)row_g * HID + u0) = hv;
            *(float4*)(out_c + (size_t)row_g * HID + u0) = cpv;
        }
        __syncthreads();   // E reads done before next phase's writes
    }
}

// ---------------------------------------------------------------------------
extern "C" void kernel_launch(void* const* d_in, const int* in_sizes, int n_in,
                              void* d_out, int out_size, void* d_ws, size_t ws_size,
                              hipStream_t stream) {
    const float* x   = (const float*)d_in[0];
    const float* h   = (const float*)d_in[1];
    const float* c   = (const float*)d_in[2];
    const float* wii = (const float*)d_in[3];
    const float* bii = (const float*)d_in[4];
    const float* wih = (const float*)d_in[5];
    const float* bih = (const float*)d_in[6];
    const float* wfi = (const float*)d_in[7];
    const float* bfi = (const float*)d_in[8];
    const float* wfh = (const float*)d_in[9];
    const float* bfh = (const float*)d_in[10];
    const float* wgi = (const float*)d_in[11];
    const float* bgi = (const float*)d_in[12];
    const float* wgh = (const float*)d_in[13];
    const float* bgh = (const float*)d_in[14];
    const float* woi = (const float*)d_in[15];
    const float* boi = (const float*)d_in[16];
    const float* woh = (const float*)d_in[17];
    const float* boh = (const float*)d_in[18];

    char* ws = (char*)d_ws;
    unsigned short* Xb  = (unsigned short*)ws;                        // 16 MB
    unsigned short* Wb  = (unsigned short*)(ws + ((size_t)16 << 20)); // 16 MB
    float*          bsv = (float*)(ws + ((size_t)32 << 20));          // 16 KB

    prep_kernel<<<8208, 256, 0, stream>>>(
        x, h, wii, wih, wfi, wfh, wgi, wgh, woi, woh,
        bii, bih, bfi, bfh, bgi, bgh, boi, boh, Xb, Wb, bsv);

    dim3 g2(BATCH / BM, NGATE / BN);
    gemm_lstm<<<g2, 1024, 0, stream>>>(Xb, Wb, bsv, c, (float*)d_out);
}

// Round 8
// 213.692 us; speedup vs baseline: 1.0409x; 1.0409x over previous
//
#include <hip/hip_runtime.h>
#include <stdint.h>

#define BATCH 4096
#define IN_DIM 1024
#define HID 1024
#define KDIM 2048      // IN + HID
#define NGATE 4096     // 4 * HID
#define EPITCH 136     // epilogue LDS row pitch (shorts); 136*2B = 16B-aligned
#define BK 64          // K-tile
#define BM 256         // M-tile
#define BN 128         // N-tile

typedef __attribute__((ext_vector_type(4))) float floatx4;
typedef __attribute__((ext_vector_type(8))) __bf16 bf16x8;
typedef __attribute__((ext_vector_type(8))) unsigned short ushort8;

__device__ __forceinline__ unsigned short f2bf(float f) {
    union { float f; unsigned int u; } v; v.f = f;
    unsigned int u = v.u;
    u += 0x7fffu + ((u >> 16) & 1u);   // RNE; inputs finite
    return (unsigned short)(u >> 16);
}
__device__ __forceinline__ float bf2f(unsigned short s) {
    union { unsigned int u; float f; } v; v.u = ((unsigned int)s) << 16;
    return v.f;
}
__device__ __forceinline__ ushort8 cvt8(const float* __restrict__ src) {
    float4 v0 = ((const float4*)src)[0];
    float4 v1 = ((const float4*)src)[1];
    ushort8 o = { f2bf(v0.x), f2bf(v0.y), f2bf(v0.z), f2bf(v0.w),
                  f2bf(v1.x), f2bf(v1.y), f2bf(v1.z), f2bf(v1.w) };
    return o;
}

// ---------------------------------------------------------------------------
// prep (block-uniform source routing):
//   X  = [x | h] bf16 (4096 x 2048)
//   W  = GATE-INTERLEAVED rows: W-row (u*4+gate) = [w_gate_i[u] | w_gate_h[u]]
//   bias[u*4+gate] = b_gate_i[u] + b_gate_h[u]
// ---------------------------------------------------------------------------
__global__ __launch_bounds__(256) void prep_kernel(
    const float* __restrict__ x,  const float* __restrict__ h,
    const float* __restrict__ wii, const float* __restrict__ wih,
    const float* __restrict__ wfi, const float* __restrict__ wfh,
    const float* __restrict__ wgi, const float* __restrict__ wgh,
    const float* __restrict__ woi, const float* __restrict__ woh,
    const float* __restrict__ bii, const float* __restrict__ bih,
    const float* __restrict__ bfi, const float* __restrict__ bfh,
    const float* __restrict__ bgi, const float* __restrict__ bgh,
    const float* __restrict__ boi, const float* __restrict__ boh,
    unsigned short* __restrict__ Xb,
    unsigned short* __restrict__ Wb,
    float* __restrict__ bias)
{
    const int bid = blockIdx.x;
    const int tid = threadIdx.x;

    if (bid < 2048) {                       // x -> Xb left half
        const int e = (bid * 256 + tid) * 8;
        const int b = e >> 10, k = e & 1023;
        *(ushort8*)(Xb + (size_t)b * KDIM + k) = cvt8(x + e);
    } else if (bid < 4096) {                // h -> Xb right half
        const int e = ((bid - 2048) * 256 + tid) * 8;
        const int b = e >> 10, k = e & 1023;
        *(ushort8*)(Xb + (size_t)b * KDIM + 1024 + k) = cvt8(h + e);
    } else if (bid < 8192) {                // weights -> interleaved W rows
        const int m   = (bid - 4096) >> 9;          // 0..7, block-uniform
        const int off = (bid - 4096) & 511;
        const int e = (off * 256 + tid) * 8;
        const int n = e >> 10, k = e & 1023;
        const float* src;
        switch (m) {
            case 0: src = wii; break; case 1: src = wih; break;
            case 2: src = wfi; break; case 3: src = wfh; break;
            case 4: src = wgi; break; case 5: src = wgh; break;
            case 6: src = woi; break; default: src = woh; break;
        }
        const int gate = m >> 1, part = m & 1;
        *(ushort8*)(Wb + (size_t)(n * 4 + gate) * KDIM + part * 1024 + k)
            = cvt8(src + e);
    } else {                                // bias: 16 blocks x 256 elems
        const int t = (bid - 8192) * 256 + tid;     // 0..4095 = gate*1024+n
        const int gate = (bid - 8192) >> 2;         // block-uniform
        const int n = t & 1023;
        const float *bi, *bh_;
        switch (gate) {
            case 0: bi = bii; bh_ = bih; break;
            case 1: bi = bfi; bh_ = bfh; break;
            case 2: bi = bgi; bh_ = bgh; break;
            default: bi = boi; bh_ = boh; break;
        }
        bias[n * 4 + gate] = bi[n] + bh_[n];
    }
}

// ---------------------------------------------------------------------------
// gemm_lstm (R6 structure — best measured: 76.6 µs):
// 256x128 tile, BK=64, 512 threads (8 waves, 64x64 each). 6 GLD16/thr/iter.
// XOR chunk swizzle (conflict-free, 131K). Fused epilogue via E[128][EPITCH].
// NEW (R8): XCD-aware block swizzle — 1D grid of 512; xcd = l&7 gets
// bx band {2*xcd, 2*xcd+1} x all by, so each XCD's A-tiles (2 MB) stay
// L2-resident while W streams.
// ---------------------------------------------------------------------------
#define GLD16(g, l)                                                          \
    __builtin_amdgcn_global_load_lds(                                        \
        (__attribute__((address_space(1))) void*)(g),                        \
        (__attribute__((address_space(3))) void*)(l), 16, 0, 0)

__global__ __launch_bounds__(512) void gemm_lstm(
    const unsigned short* __restrict__ X,
    const unsigned short* __restrict__ W,
    const float* __restrict__ bias,
    const float* __restrict__ c_in,
    float* __restrict__ out)
{
    __shared__ __align__(16) unsigned char smem[49152];      // 48 KB
    unsigned short* As = (unsigned short*)smem;              // 256*64 shorts, 32 KB
    unsigned short* Bs = (unsigned short*)(smem + 32768);    // 128*64 shorts, 16 KB
    unsigned short* E  = (unsigned short*)smem;              // 128 x EPITCH, 34.8 KB

    const int tid  = threadIdx.x;
    const int wave = tid >> 6;
    const int lane = tid & 63;
    const int quad = lane >> 4, idx = lane & 15;
    const int wm = (wave >> 1) * 64;      // 0,64,128,192
    const int wn = (wave & 1) * 64;       // 0,64

    // XCD-aware swizzle: l in [0,512); default dispatch gives xcd ~ l&7.
    const int l   = blockIdx.x;
    const int xcd = l & 7;
    const int s   = l >> 3;               // 0..63
    const int bx  = xcd * 2 + (s >> 5);   // 0..15
    const int by  = s & 31;               // 0..31
    const int rowA0 = bx * BM;
    const int rowB0 = by * BN;

    // staging: srow = tid>>3 (0..63), per-thread k-offset includes xor swizzle
    const int srow = tid >> 3;
    const int skk  = ((tid & 7) ^ (srow & 7)) * 8;
    const unsigned short* gA = X + (size_t)(rowA0 + srow) * KDIM + skk;
    const unsigned short* gB = W + (size_t)(rowB0 + srow) * KDIM + skk;
    const size_t rstride = (size_t)64 * KDIM;   // +64 rows per issue

    const int swz = (idx & 7);

    floatx4 acc[4][4] = {};

    for (int k0 = 0; k0 < KDIM; k0 += BK) {
#pragma unroll
        for (int r = 0; r < 4; ++r)
            GLD16(gA + k0 + r * rstride, As + (r * 512 + tid) * 8);
#pragma unroll
        for (int r = 0; r < 2; ++r)
            GLD16(gB + k0 + r * rstride, Bs + (r * 512 + tid) * 8);
        __syncthreads();

        bf16x8 af[4][2], bfr[4][2];
#pragma unroll
        for (int t = 0; t < 2; ++t) {
            const int co = ((t * 4 + quad) ^ swz) * 8;
#pragma unroll
            for (int i = 0; i < 4; ++i)
                af[i][t] = *(const bf16x8*)(As + (wm + i * 16 + idx) * BK + co);
#pragma unroll
            for (int j = 0; j < 4; ++j)
                bfr[j][t] = *(const bf16x8*)(Bs + (wn + j * 16 + idx) * BK + co);
        }
#pragma unroll
        for (int t = 0; t < 2; ++t)
#pragma unroll
            for (int i = 0; i < 4; ++i)
#pragma unroll
                for (int j = 0; j < 4; ++j)
                    acc[i][j] = __builtin_amdgcn_mfma_f32_16x16x32_bf16(
                        af[i][t], bfr[j][t], acc[i][j], 0, 0, 0);
        __syncthreads();
    }

    // ---- fused epilogue, two half-tile phases (rows 0-127, 128-255) ----
    const int g = idx & 3;
    const int tid8 = tid & 7;
    const int rowo = tid >> 3;           // 0..63
    float* __restrict__ out_h = out;
    float* __restrict__ out_c = out + (size_t)BATCH * HID;

#pragma unroll
    for (int half = 0; half < 2; ++half) {
        // stage 1: waves owning this half write activated gates into E
        if ((wave >> 2) == half) {
            const int wml = wm - half * 128;         // 0 or 64
#pragma unroll
            for (int j = 0; j < 4; ++j) {
                const int col = wn + j * 16 + idx;
                const float bv = bias[rowB0 + col];
#pragma unroll
                for (int i = 0; i < 4; ++i) {
#pragma unroll
                    for (int r = 0; r < 4; ++r) {
                        const int row = wml + i * 16 + quad * 4 + r;
                        const float v  = acc[i][j][r] + bv;
                        const float vv = (g == 2) ? 2.f * v : v;
                        const float s2 = 1.f / (1.f + __expf(-vv));
                        const float a  = (g == 2) ? 2.f * s2 - 1.f : s2;
                        E[row * EPITCH + col] = f2bf(a);
                    }
                }
            }
        }
        __syncthreads();

        // stage 2: all 512 threads combine 128 rows (2 passes x 64 rows)
#pragma unroll
        for (int p = 0; p < 2; ++p) {
            const int row_l = p * 64 + rowo;
            const int row_g = rowA0 + half * 128 + row_l;
            const int colc  = tid8 * 16;
            ushort8 e0 = *(const ushort8*)(E + row_l * EPITCH + colc);
            ushort8 e1 = *(const ushort8*)(E + row_l * EPITCH + colc + 8);
            const int u0 = (rowB0 >> 2) + tid8 * 4;
            const float4 cv = *(const float4*)(c_in + (size_t)row_g * HID + u0);

            float cvv[4] = { cv.x, cv.y, cv.z, cv.w };
            float hp[4], cp[4];
#pragma unroll
            for (int d = 0; d < 4; ++d) {
                const ushort8& e = (d < 2) ? e0 : e1;
                const int b = (d & 1) * 4;
                const float iv = bf2f(e[b + 0]);
                const float fv = bf2f(e[b + 1]);
                const float gv = bf2f(e[b + 2]);
                const float ov = bf2f(e[b + 3]);
                const float c2 = fv * cvv[d] + iv * gv;
                const float e2 = __expf(2.f * c2);
                cp[d] = c2;
                hp[d] = ov * ((e2 - 1.f) / (e2 + 1.f));
            }
            float4 hv  = { hp[0], hp[1], hp[2], hp[3] };
            float4 cpv = { cp[0], cp[1], cp[2], cp[3] };
            *(float4*)(out_h + (size_t)row_g * HID + u0) = hv;
            *(float4*)(out_c + (size_t)row_g * HID + u0) = cpv;
        }
        __syncthreads();   // E reads done before next half's writes
    }
}

// ---------------------------------------------------------------------------
extern "C" void kernel_launch(void* const* d_in, const int* in_sizes, int n_in,
                              void* d_out, int out_size, void* d_ws, size_t ws_size,
                              hipStream_t stream) {
    const float* x   = (const float*)d_in[0];
    const float* h   = (const float*)d_in[1];
    const float* c   = (const float*)d_in[2];
    const float* wii = (const float*)d_in[3];
    const float* bii = (const float*)d_in[4];
    const float* wih = (const float*)d_in[5];
    const float* bih = (const float*)d_in[6];
    const float* wfi = (const float*)d_in[7];
    const float* bfi = (const float*)d_in[8];
    const float* wfh = (const float*)d_in[9];
    const float* bfh = (const float*)d_in[10];
    const float* wgi = (const float*)d_in[11];
    const float* bgi = (const float*)d_in[12];
    const float* wgh = (const float*)d_in[13];
    const float* bgh = (const float*)d_in[14];
    const float* woi = (const float*)d_in[15];
    const float* boi = (const float*)d_in[16];
    const float* woh = (const float*)d_in[17];
    const float* boh = (const float*)d_in[18];

    char* ws = (char*)d_ws;
    unsigned short* Xb  = (unsigned short*)ws;                        // 16 MB
    unsigned short* Wb  = (unsigned short*)(ws + ((size_t)16 << 20)); // 16 MB
    float*          bsv = (float*)(ws + ((size_t)32 << 20));          // 16 KB

    prep_kernel<<<8208, 256, 0, stream>>>(
        x, h, wii, wih, wfi, wfh, wgi, wgh, woi, woh,
        bii, bih, bfi, bfh, bgi, bgh, boi, boh, Xb, Wb, bsv);

    gemm_lstm<<<(BATCH / BM) * (NGATE / BN), 512, 0, stream>>>(
        Xb, Wb, bsv, c, (float*)d_out);
}